// Round 8
// baseline (168.957 us; speedup 1.0000x reference)
//
#include <hip/hip_runtime.h>
#include <stdint.h>

typedef __attribute__((ext_vector_type(8))) short short8;
typedef __attribute__((ext_vector_type(4))) float f32x4;
typedef __attribute__((ext_vector_type(8))) float f32x8;
typedef __bf16 bf16x8_t __attribute__((ext_vector_type(8)));

#define NN     784             // 28*28
#define NIMG   16              // images per block
#define NA     28              // output rows (a)
#define NSLOT  8               // K-slots of 32 per a (256-wide window covers the 196 band)
#define NT     25              // x K-slots (784 -> 25*32)
#define FRAG_U16 512           // ushorts per 16x32 fragment
#define ABYTES  (NSLOT * 2 * FRAG_U16 * 2)   // 16384 B of W-table per a

__device__ __forceinline__ unsigned short f2bf(float f) {
  unsigned int u = __float_as_uint(f);
  return (unsigned short)((u + 0x7FFFu + ((u >> 16) & 1u)) >> 16);  // RNE, finite inputs
}

__device__ __forceinline__ short8 cvt8(f32x4 lo, f32x4 hi) {
  f32x8 f = {lo.x, lo.y, lo.z, lo.w, hi.x, hi.y, hi.z, hi.w};
  bf16x8_t b = __builtin_convertvector(f, bf16x8_t);   // v_cvt_pk_bf16_f32 (RNE)
  return __builtin_bit_cast(short8, b);
}

// First stored k-slot for output row a: 32-aligned window start covering
// k in [28(a-3), 28(a+4)), clamped so slots s=0..7 stay in [0,24].
__host__ __device__ constexpr int slot0c(int a) {
  int t = 28 * a - 84;
  if (t < 0) t = 0;
  t >>= 5;
  if (t > 17) t = 17;
  return t;
}

// Bpack[a][s][nf] = 1KB MFMA W-fragment (16 outcols x 32 k), frag-contiguous.
// In-frag u16 index for (outcol rl, k kk): ((kk>>3)*16 + rl)*8 + (kk&7).
// Value = weight[a*28+ncol] * W[a*28+ncol][kglob], 0 outside grid/band.
__global__ void build_w_kernel(const float* __restrict__ pos2d,
                               const float* __restrict__ weight,
                               const float* __restrict__ ep,
                               unsigned short* __restrict__ Bpack) {
  int idx = blockIdx.x * 256 + threadIdx.x;   // 0 .. 28*8*2*512-1
  int u    = idx & 511;
  int frag = idx >> 9;          // ((a*8 + s)*2 + nf)
  int nf = frag & 1;
  int s  = (frag >> 1) & 7;
  int a  = frag >> 4;
  int j8   = u & 7;
  int lane = u >> 3;
  int rl = lane & 15;
  int ch = lane >> 4;
  int kk = ch * 8 + j8;                        // 0..31
  int kglob = (slot0c(a) + s) * 32 + kk;
  int ncol  = nf * 16 + rl;
  float val = 0.f;
  if (ncol < 28 && kglob < NN) {
    float px = pos2d[2 * kglob + 0];
    float py = pos2d[2 * kglob + 1];
    float dx = (float)ncol - px;
    float dy = (float)a - py;
    float d2 = __fadd_rn(__fmul_rn(dx, dx), __fmul_rn(dy, dy));  // match np (no fma)
    if (d2 < 9.0f) {
      float en = fminf(ep[kglob], 0.f);
      val = expf(en * d2) * weight[a * 28 + ncol];
    }
  }
  Bpack[idx] = f2bf(val);
}

// Per-wave-independent banded GEMM.
// Block = 16 images, 4 waves. x staged ONCE to LDS in fragment layout (one
// barrier total); wave w then privately computes a = w, w+4, ..., w+24:
// W half-tiles (8 frags) stream global->registers (L2-resident, coalesced,
// 2-deep software pipeline), x-frags via conflict-free ds_read_b128,
// 16 MFMAs (swapped operands), 2 contiguous dwordx4 stores per a.
// No loop barriers; compiler emits exact counted waitcnts on registers.
__global__ __launch_bounds__(256, 3)
void gemm_kernel(const float* __restrict__ x,
                 const unsigned short* __restrict__ Bpack,
                 float* __restrict__ out) {
  __shared__ unsigned short xlds[NT * FRAG_U16];   // 25 KB: [t][lane][8k]

  const int tid  = threadIdx.x;
  const int wave = tid >> 6;
  const int lane = tid & 63;
  const int rl   = lane & 15;       // image slot / W-frag outcol
  const int ch   = lane >> 4;       // k-chunk of 8
  const int m0   = blockIdx.x * NIMG;

  // --- W prefetch for this wave's first a, half 0 (fire-and-forget) ---
  const char* wbase = (const char*)Bpack + lane * 16;
  short8 wf0[8], wf1[8];
  {
    const char* p = wbase + (size_t)wave * ABYTES;   // a = wave, half 0
    #pragma unroll
    for (int f = 0; f < 8; ++f)
      wf0[f] = *(const short8*)(p + f * 1024);
  }

  // --- stage x -> LDS in fragment layout: entry e = t*64 + l ---
  // l -> (img = l&15, k = t*32 + (l>>4)*8 .. +8)
  #pragma unroll
  for (int i = 0; i < 7; ++i) {
    int e = i * 256 + tid;
    if (e < NT * 64) {
      int t = e >> 6, l = e & 63;
      int img = l & 15;
      int k = t * 32 + (l >> 4) * 8;
      f32x4 lo = (f32x4){0.f, 0.f, 0.f, 0.f};
      f32x4 hi = (f32x4){0.f, 0.f, 0.f, 0.f};
      if (k + 8 <= NN) {                       // only (t=24, ch>=2) excluded
        const float* p = x + (size_t)(m0 + img) * NN + k;
        lo = *(const f32x4*)p;
        hi = *(const f32x4*)(p + 4);
      }
      *(short8*)((char*)xlds + e * 16) = cvt8(lo, hi);
    }
  }
  __syncthreads();                             // the ONLY block barrier

  const char* xbase = (const char*)xlds + lane * 16;
  float* orow = out + (size_t)(m0 + rl) * NN;

  #pragma unroll
  for (int j = 0; j < 7; ++j) {
    const int a = wave + 4 * j;
    const char* wp = wbase + (size_t)a * ABYTES;

    // issue half 1 of this a
    #pragma unroll
    for (int f = 0; f < 8; ++f)
      wf1[f] = *(const short8*)(wp + 8192 + f * 1024);

    // x fragments for this a's window (conflict-free ds_read_b128)
    const int t0 = slot0c(a);                  // runtime (wave), fine for addresses
    short8 xf[8];
    #pragma unroll
    for (int s = 0; s < 8; ++s)
      xf[s] = *(const short8*)(xbase + (t0 + s) * 1024);

    f32x4 acc0 = (f32x4){0.f, 0.f, 0.f, 0.f};
    f32x4 acc1 = (f32x4){0.f, 0.f, 0.f, 0.f};

    // first half: frags 0..7 = s-pairs 0..3
    #pragma unroll
    for (int s = 0; s < 4; ++s) {
      acc0 = __builtin_amdgcn_mfma_f32_16x16x32_bf16(wf0[2 * s + 0], xf[s], acc0, 0, 0, 0);
      acc1 = __builtin_amdgcn_mfma_f32_16x16x32_bf16(wf0[2 * s + 1], xf[s], acc1, 0, 0, 0);
    }

    // issue half 0 of next a (2-deep pipeline across iterations)
    if (j < 6) {
      const char* np = wbase + (size_t)(a + 4) * ABYTES;
      #pragma unroll
      for (int f = 0; f < 8; ++f)
        wf0[f] = *(const short8*)(np + f * 1024);
    }

    // second half: frags 8..15 = s-pairs 4..7
    #pragma unroll
    for (int s = 4; s < 8; ++s) {
      acc0 = __builtin_amdgcn_mfma_f32_16x16x32_bf16(wf1[2 * (s - 4) + 0], xf[s], acc0, 0, 0, 0);
      acc1 = __builtin_amdgcn_mfma_f32_16x16x32_bf16(wf1[2 * (s - 4) + 1], xf[s], acc1, 0, 0, 0);
    }

    // C'[outcol, image]: lane holds image rl, outcols ch*4+{0..3} (+16 for acc1).
    float* op = orow + a * 28 + ch * 4;
    *(f32x4*)op = acc0;                        // global_store_dwordx4
    if (ch < 3) *(f32x4*)(op + 16) = acc1;     // outcols 16..27 only
  }
}

extern "C" void kernel_launch(void* const* d_in, const int* in_sizes, int n_in,
                              void* d_out, int out_size, void* d_ws, size_t ws_size,
                              hipStream_t stream) {
  const float* x      = (const float*)d_in[0];
  const float* pos2d  = (const float*)d_in[1];
  const float* weight = (const float*)d_in[2];
  const float* ep     = (const float*)d_in[3];
  float* out          = (float*)d_out;
  unsigned short* Bpack = (unsigned short*)d_ws;        // 28*8*2*512*2 = 458,752 B

  int batch = in_sizes[0] / NN;                         // 65536

  build_w_kernel<<<dim3((NA * NSLOT * 2 * FRAG_U16) / 256), dim3(256), 0, stream>>>(
      pos2d, weight, ep, Bpack);
  gemm_kernel<<<dim3(batch / NIMG), dim3(256), 0, stream>>>(x, Bpack, out);
}

// Round 9
// 143.311 us; speedup vs baseline: 1.1790x; 1.1790x over previous
//
#include <hip/hip_runtime.h>
#include <stdint.h>

typedef __attribute__((ext_vector_type(8))) short short8;
typedef __attribute__((ext_vector_type(4))) float f32x4;
typedef __attribute__((ext_vector_type(8))) float f32x8;
typedef __bf16 bf16x8_t __attribute__((ext_vector_type(8)));

#define NN     784             // 28*28
#define NIMG   16              // images per block
#define NA     28              // output rows (a)
#define NSLOT  8               // K-slots of 32 per a (256-wide window covers the 196 band)
#define NT     25              // x K-slots (784 -> 25*32)
#define FRAG_U16 512           // ushorts per 16x32 fragment
#define ABYTES  (NSLOT * 2 * FRAG_U16 * 2)   // 16384 B of W-table per a

__device__ __forceinline__ unsigned short f2bf(float f) {
  unsigned int u = __float_as_uint(f);
  return (unsigned short)((u + 0x7FFFu + ((u >> 16) & 1u)) >> 16);  // RNE, finite inputs
}

__device__ __forceinline__ short8 cvt8(f32x4 lo, f32x4 hi) {
  f32x8 f = {lo.x, lo.y, lo.z, lo.w, hi.x, hi.y, hi.z, hi.w};
  bf16x8_t b = __builtin_convertvector(f, bf16x8_t);   // v_cvt_pk_bf16_f32 (RNE)
  return __builtin_bit_cast(short8, b);
}

// First stored k-slot for output row a: 32-aligned window start covering
// k in [28(a-3), 28(a+4)), clamped so slots s=0..7 stay in [0,24].
__host__ __device__ constexpr int slot0c(int a) {
  int t = 28 * a - 84;
  if (t < 0) t = 0;
  t >>= 5;
  if (t > 17) t = 17;
  return t;
}

// Bpack[a][s][nf] = 1KB MFMA W-fragment (16 outcols x 32 k), frag-contiguous.
// In-frag u16 index for (outcol rl, k kk): ((kk>>3)*16 + rl)*8 + (kk&7).
// Value = weight[a*28+ncol] * W[a*28+ncol][kglob], 0 outside grid/band.
__global__ void build_w_kernel(const float* __restrict__ pos2d,
                               const float* __restrict__ weight,
                               const float* __restrict__ ep,
                               unsigned short* __restrict__ Bpack) {
  int idx = blockIdx.x * 256 + threadIdx.x;   // 0 .. 28*8*2*512-1
  int u    = idx & 511;
  int frag = idx >> 9;          // ((a*8 + s)*2 + nf)
  int nf = frag & 1;
  int s  = (frag >> 1) & 7;
  int a  = frag >> 4;
  int j8   = u & 7;
  int lane = u >> 3;
  int rl = lane & 15;
  int ch = lane >> 4;
  int kk = ch * 8 + j8;                        // 0..31
  int kglob = (slot0c(a) + s) * 32 + kk;
  int ncol  = nf * 16 + rl;
  float val = 0.f;
  if (ncol < 28 && kglob < NN) {
    float px = pos2d[2 * kglob + 0];
    float py = pos2d[2 * kglob + 1];
    float dx = (float)ncol - px;
    float dy = (float)a - py;
    float d2 = __fadd_rn(__fmul_rn(dx, dx), __fmul_rn(dy, dy));  // match np (no fma)
    if (d2 < 9.0f) {
      float en = fminf(ep[kglob], 0.f);
      val = expf(en * d2) * weight[a * 28 + ncol];
    }
  }
  Bpack[idx] = f2bf(val);
}

// Per-wave-independent banded GEMM with LDS out-tile (coalesced store flush).
// Block = 16 images, 4 waves. x staged once to LDS (fragment layout); wave w
// privately computes a = w, w+4, ..., w+24: W half-tiles stream L2->registers
// (2-deep pipeline), x-frags via ds_read_b128, 16 MFMAs (swapped operands).
// acc frags go to an LDS out-tile [16][784] f32; after one barrier the block
// flushes it with fully-contiguous 1KB-per-instruction stores.
__global__ __launch_bounds__(256, 2)
void gemm_kernel(const float* __restrict__ x,
                 const unsigned short* __restrict__ Bpack,
                 float* __restrict__ out) {
  __shared__ unsigned short xlds[NT * FRAG_U16];   // 25600 B: [t][lane][8k]
  __shared__ float olds[NIMG * NN];                // 50176 B: [img][784]

  const int tid  = threadIdx.x;
  const int wave = tid >> 6;
  const int lane = tid & 63;
  const int rl   = lane & 15;       // image slot / W-frag outcol
  const int ch   = lane >> 4;       // k-chunk of 8
  const int m0   = blockIdx.x * NIMG;

  // --- W prefetch for this wave's first a, half 0 (fire-and-forget) ---
  const char* wbase = (const char*)Bpack + lane * 16;
  short8 wf0[8], wf1[8];
  {
    const char* p = wbase + (size_t)wave * ABYTES;   // a = wave, half 0
    #pragma unroll
    for (int f = 0; f < 8; ++f)
      wf0[f] = *(const short8*)(p + f * 1024);
  }

  // --- stage x -> LDS in fragment layout: entry e = t*64 + l ---
  // l -> (img = l&15, k = t*32 + (l>>4)*8 .. +8)
  #pragma unroll
  for (int i = 0; i < 7; ++i) {
    int e = i * 256 + tid;
    if (e < NT * 64) {
      int t = e >> 6, l = e & 63;
      int img = l & 15;
      int k = t * 32 + (l >> 4) * 8;
      f32x4 lo = (f32x4){0.f, 0.f, 0.f, 0.f};
      f32x4 hi = (f32x4){0.f, 0.f, 0.f, 0.f};
      if (k + 8 <= NN) {                       // only (t=24, ch>=2) excluded
        const float* p = x + (size_t)(m0 + img) * NN + k;
        lo = *(const f32x4*)p;
        hi = *(const f32x4*)(p + 4);
      }
      *(short8*)((char*)xlds + e * 16) = cvt8(lo, hi);
    }
  }
  __syncthreads();                             // x-tile ready

  const char* xbase = (const char*)xlds + lane * 16;
  char* obase = (char*)olds + rl * (NN * 4) + ch * 16;   // [img=rl] row

  #pragma unroll
  for (int j = 0; j < 7; ++j) {
    const int a = wave + 4 * j;
    const char* wp = wbase + (size_t)a * ABYTES;

    // issue half 1 of this a
    #pragma unroll
    for (int f = 0; f < 8; ++f)
      wf1[f] = *(const short8*)(wp + 8192 + f * 1024);

    // x fragments for this a's window (conflict-free ds_read_b128)
    const int t0 = slot0c(a);                  // runtime (wave), addresses only
    short8 xf[8];
    #pragma unroll
    for (int s = 0; s < 8; ++s)
      xf[s] = *(const short8*)(xbase + (t0 + s) * 1024);

    f32x4 acc0 = (f32x4){0.f, 0.f, 0.f, 0.f};
    f32x4 acc1 = (f32x4){0.f, 0.f, 0.f, 0.f};

    // first half: frags 0..7 = s-pairs 0..3
    #pragma unroll
    for (int s = 0; s < 4; ++s) {
      acc0 = __builtin_amdgcn_mfma_f32_16x16x32_bf16(wf0[2 * s + 0], xf[s], acc0, 0, 0, 0);
      acc1 = __builtin_amdgcn_mfma_f32_16x16x32_bf16(wf0[2 * s + 1], xf[s], acc1, 0, 0, 0);
    }

    // issue half 0 of next a (2-deep pipeline across iterations)
    if (j < 6) {
      const char* np = wbase + (size_t)(a + 4) * ABYTES;
      #pragma unroll
      for (int f = 0; f < 8; ++f)
        wf0[f] = *(const short8*)(np + f * 1024);
    }

    // second half: frags 8..15 = s-pairs 4..7
    #pragma unroll
    for (int s = 4; s < 8; ++s) {
      acc0 = __builtin_amdgcn_mfma_f32_16x16x32_bf16(wf1[2 * (s - 4) + 0], xf[s], acc0, 0, 0, 0);
      acc1 = __builtin_amdgcn_mfma_f32_16x16x32_bf16(wf1[2 * (s - 4) + 1], xf[s], acc1, 0, 0, 0);
    }

    // C'[outcol, image] -> LDS out-tile (waves own disjoint a -> no races).
    // lane writes image rl, outcols a*28 + ch*4 + {0..3} (+16 for acc1).
    char* op = obase + a * 112;
    *(f32x4*)op = acc0;                        // ds_write_b128, uniform bank spread
    if (ch < 3) *(f32x4*)(op + 64) = acc1;     // outcols 16..27 only
  }

  __syncthreads();                             // out-tile complete

  // --- coalesced flush: 16-B granule e, lds [img][784] == out row-major ---
  float* oglob = out + (size_t)m0 * NN;
  #pragma unroll
  for (int i = 0; i < 13; ++i) {
    int e = i * 256 + tid;
    if (e < NIMG * NN / 4) {
      f32x4 v = *(const f32x4*)((const char*)olds + e * 16);
      *(f32x4*)((char*)oglob + e * 16) = v;    // 1KB contiguous per wave-instr
    }
  }
}

extern "C" void kernel_launch(void* const* d_in, const int* in_sizes, int n_in,
                              void* d_out, int out_size, void* d_ws, size_t ws_size,
                              hipStream_t stream) {
  const float* x      = (const float*)d_in[0];
  const float* pos2d  = (const float*)d_in[1];
  const float* weight = (const float*)d_in[2];
  const float* ep     = (const float*)d_in[3];
  float* out          = (float*)d_out;
  unsigned short* Bpack = (unsigned short*)d_ws;        // 28*8*2*512*2 = 458,752 B

  int batch = in_sizes[0] / NN;                         // 65536

  build_w_kernel<<<dim3((NA * NSLOT * 2 * FRAG_U16) / 256), dim3(256), 0, stream>>>(
      pos2d, weight, ep, Bpack);
  gemm_kernel<<<dim3(batch / NIMG), dim3(256), 0, stream>>>(x, Bpack, out);
}